// Round 10
// baseline (149.299 us; speedup 1.0000x reference)
//
#include <hip/hip_runtime.h>

#define NB 4
#define SLQ 256
#define SLK 256
#define DD 768

// tanh(x) = 1 - 2/(1+e^{2x});  e^{2(q+k)} = exp2(q*2log2e)*exp2(k*2log2e).
// Softmax-invariant constants (sum Ws + bs) dropped from the logits.
#define TWO_LOG2E 2.8853900817779268f
#define LOG2E 1.4426950408889634f

typedef _Float16 f16x4 __attribute__((ext_vector_type(4)));
typedef _Float16 f16x8 __attribute__((ext_vector_type(8)));
typedef float f32x4 __attribute__((ext_vector_type(4)));

__device__ __forceinline__ float fexp2(float x) { return __builtin_amdgcn_exp2f(x); }
__device__ __forceinline__ float frcp(float x) { return __builtin_amdgcn_rcpf(x); }

#define KSTR 72            // LDS row stride (halves) for BK=64 MFMA tiles
#define TSTR 72            // LDS row stride (halves) for f16 epilogue transpose
#define TFSTR 65           // LDS row stride (floats) for f32 epilogue restage
#define PSTR 264           // LDS row stride (halves) for fused P/V tiles
#define NPS  ((size_t)NB * SLQ * SLK)   // elements per scores-partial slice

// ---------------- Prep: W [in][out] fp32 -> Wt [out][in] fp16 ----------------
__global__ __launch_bounds__(256) void prep_wt_kernel(
    const float* __restrict__ Wq, const float* __restrict__ Wk,
    const float* __restrict__ Wv, _Float16* __restrict__ wtq,
    _Float16* __restrict__ wtk, _Float16* __restrict__ wtv)
{
    const int z = blockIdx.z;
    const float* W = (z == 0) ? Wq : (z == 1) ? Wk : Wv;
    _Float16* Wt = (z == 0) ? wtq : (z == 1) ? wtk : wtv;

    __shared__ float t[64][65];
    const int tid = threadIdx.x;
    const int kt0 = blockIdx.y * 64;
    const int nt0 = blockIdx.x * 64;

    const int col4 = (tid & 15) << 2;
#pragma unroll
    for (int i = 0; i < 4; ++i) {
        const int row = ((tid >> 4) << 2) + i;
        *(float4*)&t[row][col4] = *(const float4*)&W[(size_t)(kt0 + row) * DD + nt0 + col4];
    }
    __syncthreads();
    const int n = tid >> 2;
    const int k16 = (tid & 3) << 4;
    f16x8 h0, h1;
#pragma unroll
    for (int j = 0; j < 8; ++j) {
        h0[j] = (_Float16)t[k16 + j][n];
        h1[j] = (_Float16)t[k16 + 8 + j][n];
    }
    *(f16x8*)&Wt[(size_t)(nt0 + n) * DD + kt0 + k16] = h0;
    *(f16x8*)&Wt[(size_t)(nt0 + n) * DD + kt0 + k16 + 8] = h1;
}

// ---------------- QKV projection, fp16 MFMA, BK=64 (12 barriers) ----------------
// z=0 -> eq f32 = exp2(q*2log2e); z=1 -> ekc f16 chunked [b][d/8][k][8];
// z=2 -> vsht f16 = v^T [b][col][k] via LDS transpose.
__global__ __launch_bounds__(256) void qkv_f16_kernel(
    const float* __restrict__ query, const float* __restrict__ key_in,
    const float* __restrict__ value, const _Float16* __restrict__ wtq,
    const _Float16* __restrict__ wtk, const _Float16* __restrict__ wtv,
    const float* __restrict__ bq, const float* __restrict__ bk,
    const float* __restrict__ bv, float* __restrict__ eq,
    _Float16* __restrict__ ekc, _Float16* __restrict__ vsht)
{
    const int z = blockIdx.z;
    const float* A = (z == 0) ? query : (z == 1) ? key_in : value;
    const _Float16* Wt = (z == 0) ? wtq : (z == 1) ? wtk : wtv;
    const float* bias = (z == 0) ? bq : (z == 1) ? bk : bv;

    __shared__ _Float16 Sh[2][2][64 * KSTR];   // 36864 B; reused by epilogues

    const int tid = threadIdx.x;
    const int lane = tid & 63;
    const int wid = tid >> 6;
    const int wr = wid >> 1;
    const int wc = wid & 1;
    const int row0 = blockIdx.y * 64;
    const int col0 = blockIdx.x * 64;

    const int sr = tid >> 2;          // row / out-col 0..63
    const int sc = (tid & 3) << 4;    // k offset 0,16,32,48

    const float* Ap = A + (size_t)(row0 + sr) * DD + sc;
    const _Float16* Bp = Wt + (size_t)(col0 + sr) * DD + sc;

    float4 pa0 = *(const float4*)Ap;
    float4 pa1 = *(const float4*)(Ap + 4);
    float4 pa2 = *(const float4*)(Ap + 8);
    float4 pa3 = *(const float4*)(Ap + 12);
    f16x8 pb0 = *(const f16x8*)Bp;
    f16x8 pb1 = *(const f16x8*)(Bp + 8);

    f32x4 acc[2][2] = {};
    const int kj = (lane >> 4) << 3;
    const int fr = lane & 15;

    {
        f16x8 ha;
        ha[0] = (_Float16)pa0.x; ha[1] = (_Float16)pa0.y;
        ha[2] = (_Float16)pa0.z; ha[3] = (_Float16)pa0.w;
        ha[4] = (_Float16)pa1.x; ha[5] = (_Float16)pa1.y;
        ha[6] = (_Float16)pa1.z; ha[7] = (_Float16)pa1.w;
        *(f16x8*)&Sh[0][0][sr * KSTR + sc] = ha;
        ha[0] = (_Float16)pa2.x; ha[1] = (_Float16)pa2.y;
        ha[2] = (_Float16)pa2.z; ha[3] = (_Float16)pa2.w;
        ha[4] = (_Float16)pa3.x; ha[5] = (_Float16)pa3.y;
        ha[6] = (_Float16)pa3.z; ha[7] = (_Float16)pa3.w;
        *(f16x8*)&Sh[0][0][sr * KSTR + sc + 8] = ha;
        *(f16x8*)&Sh[0][1][sr * KSTR + sc] = pb0;
        *(f16x8*)&Sh[0][1][sr * KSTR + sc + 8] = pb1;
    }
    __syncthreads();

    int p = 0;
    for (int s = 0; s < DD / 64; ++s) {
        if (s + 1 < DD / 64) {
            const int ks = (s + 1) * 64;
            pa0 = *(const float4*)(Ap + ks);
            pa1 = *(const float4*)(Ap + ks + 4);
            pa2 = *(const float4*)(Ap + ks + 8);
            pa3 = *(const float4*)(Ap + ks + 12);
            pb0 = *(const f16x8*)(Bp + ks);
            pb1 = *(const f16x8*)(Bp + ks + 8);
        }
        // 8 MFMA: 2 row-frags x 2 col-frags x 2 k-halves
#pragma unroll
        for (int h = 0; h < 2; ++h) {
            const int ko = h * 32 + kj;
            f16x8 af0 = *(const f16x8*)&Sh[p][0][(wr * 32 + fr) * KSTR + ko];
            f16x8 af1 = *(const f16x8*)&Sh[p][0][(wr * 32 + 16 + fr) * KSTR + ko];
            f16x8 bf0 = *(const f16x8*)&Sh[p][1][(wc * 32 + fr) * KSTR + ko];
            f16x8 bf1 = *(const f16x8*)&Sh[p][1][(wc * 32 + 16 + fr) * KSTR + ko];
            acc[0][0] = __builtin_amdgcn_mfma_f32_16x16x32_f16(af0, bf0, acc[0][0], 0, 0, 0);
            acc[0][1] = __builtin_amdgcn_mfma_f32_16x16x32_f16(af0, bf1, acc[0][1], 0, 0, 0);
            acc[1][0] = __builtin_amdgcn_mfma_f32_16x16x32_f16(af1, bf0, acc[1][0], 0, 0, 0);
            acc[1][1] = __builtin_amdgcn_mfma_f32_16x16x32_f16(af1, bf1, acc[1][1], 0, 0, 0);
        }
        if (s + 1 < DD / 64) {
            f16x8 ha;
            ha[0] = (_Float16)pa0.x; ha[1] = (_Float16)pa0.y;
            ha[2] = (_Float16)pa0.z; ha[3] = (_Float16)pa0.w;
            ha[4] = (_Float16)pa1.x; ha[5] = (_Float16)pa1.y;
            ha[6] = (_Float16)pa1.z; ha[7] = (_Float16)pa1.w;
            *(f16x8*)&Sh[p ^ 1][0][sr * KSTR + sc] = ha;
            ha[0] = (_Float16)pa2.x; ha[1] = (_Float16)pa2.y;
            ha[2] = (_Float16)pa2.z; ha[3] = (_Float16)pa2.w;
            ha[4] = (_Float16)pa3.x; ha[5] = (_Float16)pa3.y;
            ha[6] = (_Float16)pa3.z; ha[7] = (_Float16)pa3.w;
            *(f16x8*)&Sh[p ^ 1][0][sr * KSTR + sc + 8] = ha;
            *(f16x8*)&Sh[p ^ 1][1][sr * KSTR + sc] = pb0;
            *(f16x8*)&Sh[p ^ 1][1][sr * KSTR + sc + 8] = pb1;
        }
        __syncthreads();
        p ^= 1;
    }

    // C/D layout: col = lane&15, row = (lane>>4)*4 + reg [m89 verified]
    const int clb = wc * 32 + fr;
    const int rlb = wr * 32 + ((lane >> 4) << 2);

    if (z < 2) {
        float* Tf = (float*)Sh;   // [64][TFSTR] = 16.6 KB
#pragma unroll
        for (int mf = 0; mf < 2; ++mf) {
#pragma unroll
            for (int nf = 0; nf < 2; ++nf) {
                const int cl = clb + nf * 16;
                const float bvv = bias[col0 + cl];
#pragma unroll
                for (int r = 0; r < 4; ++r) {
                    const int rl = rlb + mf * 16 + r;
                    const float arg = fminf((acc[mf][nf][r] + bvv) * TWO_LOG2E, 15.0f);
                    Tf[rl * TFSTR + cl] = fexp2(arg);
                }
            }
        }
        __syncthreads();
        if (z == 0) {
#pragma unroll
            for (int j = 0; j < 4; ++j) {
                const int u = tid + j * 256;
                const int row = u >> 4;
                const int c4 = (u & 15) << 2;
                float4 v = *(const float4*)&Tf[row * TFSTR + c4];
                *(float4*)&eq[(size_t)(row0 + row) * DD + col0 + c4] = v;
            }
        } else {
            const int b = row0 >> 8;
            const int krow0 = row0 & 255;
            const size_t base = (size_t)b * (SLK * DD) + (size_t)(col0 >> 3) * (SLK * 8);
#pragma unroll
            for (int j = 0; j < 2; ++j) {
                const int u = tid + j * 256;
                const int c2 = u >> 6;
                const int k = u & 63;
                const float* src = &Tf[k * TFSTR + c2 * 8];
                f16x8 h;
#pragma unroll
                for (int i = 0; i < 8; ++i) h[i] = (_Float16)src[i];
                *(f16x8*)&ekc[base + (size_t)c2 * (SLK * 8) + (size_t)(krow0 + k) * 8] = h;
            }
        }
    } else {
        _Float16* T = (_Float16*)Sh;   // 64 cols x TSTR = 9.2 KB
#pragma unroll
        for (int mf = 0; mf < 2; ++mf) {
#pragma unroll
            for (int nf = 0; nf < 2; ++nf) {
                const int cl = clb + nf * 16;
                const float bvv = bias[col0 + cl];
                const int rl = rlb + mf * 16;
                f16x4 h;
#pragma unroll
                for (int r = 0; r < 4; ++r) h[r] = (_Float16)(acc[mf][nf][r] + bvv);
                *(f16x4*)&T[cl * TSTR + rl] = h;
            }
        }
        __syncthreads();
        const int b = row0 >> 8;
        const int krow0 = row0 & 255;
#pragma unroll
        for (int j = 0; j < 2; ++j) {
            const int u = tid + 256 * j;
            const int c2 = u >> 3;
            const int g = u & 7;
            f16x8 hv = *(const f16x8*)&T[c2 * TSTR + g * 8];
            *(f16x8*)&vsht[((size_t)b * DD + col0 + c2) * SLK + krow0 + g * 8] = hv;
        }
    }
}

// ---------------- Scores partial (d-split S=4, 2 q-rows/thread, pairwise rcp) ----------------
__global__ __launch_bounds__(256) void scores_partial_kernel(
    const float* __restrict__ Eq, const _Float16* __restrict__ Ekc,
    const float* __restrict__ Ws, float* __restrict__ pbuf)
{
    const int bz = blockIdx.z;
    const int b = bz >> 2;
    const int s = bz & 3;
    const int k0 = blockIdx.x * 64;
    const int q0 = blockIdx.y * 8;
    const int lane = threadIdx.x & 63;
    const int wid = __builtin_amdgcn_readfirstlane((int)(threadIdx.x >> 6));
    const int q = q0 + (wid << 1);
    const int d0 = s * 192;

    const _Float16* kr = Ekc + (size_t)b * (SLK * DD) + ((d0 >> 3) * (SLK * 8)) +
                         (k0 + lane) * 8;
    const float* qp0 = Eq + (size_t)(b * SLQ + q) * DD + d0;
    const float* qp1 = qp0 + DD;
    const float* wp = Ws + d0;

    float acc0 = 0.f, acc1 = 0.f;

#pragma unroll 4
    for (int c = 0; c < 24; ++c) {
        const int dn = c * 8;
        f16x8 e = *(const f16x8*)(kr + (size_t)c * (SLK * 8));
        float4 ga0 = *(const float4*)(qp0 + dn);
        float4 ga1 = *(const float4*)(qp0 + dn + 4);
        float4 gb0 = *(const float4*)(qp1 + dn);
        float4 gb1 = *(const float4*)(qp1 + dn + 4);
        float4 w0 = *(const float4*)(wp + dn);
        float4 w1 = *(const float4*)(wp + dn + 4);

        float e0 = (float)e[0], e1 = (float)e[1], e2 = (float)e[2], e3 = (float)e[3];
        float e4 = (float)e[4], e5 = (float)e[5], e6 = (float)e[6], e7 = (float)e[7];

        {
            float A0 = fmaf(ga0.x, e0, 1.0f), A1 = fmaf(ga0.y, e1, 1.0f);
            float A2 = fmaf(ga0.z, e2, 1.0f), A3 = fmaf(ga0.w, e3, 1.0f);
            float A4 = fmaf(ga1.x, e4, 1.0f), A5 = fmaf(ga1.y, e5, 1.0f);
            float A6 = fmaf(ga1.z, e6, 1.0f), A7 = fmaf(ga1.w, e7, 1.0f);
            acc0 = fmaf(fmaf(w0.x, A1, w0.y * A0), frcp(A0 * A1), acc0);
            acc0 = fmaf(fmaf(w0.z, A3, w0.w * A2), frcp(A2 * A3), acc0);
            acc0 = fmaf(fmaf(w1.x, A5, w1.y * A4), frcp(A4 * A5), acc0);
            acc0 = fmaf(fmaf(w1.z, A7, w1.w * A6), frcp(A6 * A7), acc0);
        }
        {
            float A0 = fmaf(gb0.x, e0, 1.0f), A1 = fmaf(gb0.y, e1, 1.0f);
            float A2 = fmaf(gb0.z, e2, 1.0f), A3 = fmaf(gb0.w, e3, 1.0f);
            float A4 = fmaf(gb1.x, e4, 1.0f), A5 = fmaf(gb1.y, e5, 1.0f);
            float A6 = fmaf(gb1.z, e6, 1.0f), A7 = fmaf(gb1.w, e7, 1.0f);
            acc1 = fmaf(fmaf(w0.x, A1, w0.y * A0), frcp(A0 * A1), acc1);
            acc1 = fmaf(fmaf(w0.z, A3, w0.w * A2), frcp(A2 * A3), acc1);
            acc1 = fmaf(fmaf(w1.x, A5, w1.y * A4), frcp(A4 * A5), acc1);
            acc1 = fmaf(fmaf(w1.z, A7, w1.w * A6), frcp(A6 * A7), acc1);
        }
    }

    const size_t o = (size_t)s * NPS + (size_t)(b * SLQ + q) * SLK + k0 + lane;
    pbuf[o] = -2.0f * acc0;
    pbuf[o + SLK] = -2.0f * acc1;
}

// ---------------- Fused: combine partials + softmax + P@V, barrier-free K-loop ----------------
// Block: 64 rows x 32 out-cols. Softmax in-register (statically unrolled float4[16]).
// P (f16) written straight into LDS; V panel staged whole; 16 MFMA with ONE barrier.
// Col-tile 0 also writes the attnw output (f32 probabilities).
__global__ __launch_bounds__(256) void attended_fused_kernel(
    const float* __restrict__ pbuf, const _Float16* __restrict__ vsht,
    float* __restrict__ attnw, float* __restrict__ out)
{
    __shared__ _Float16 Pl[64 * PSTR];   // 33.8 KB
    __shared__ _Float16 Vl[32 * PSTR];   // 16.9 KB

    const int tid = threadIdx.x;
    const int row0 = blockIdx.y * 64;    // global row 0..960
    const int col0 = blockIdx.x * 32;
    const int b = row0 >> 8;

    // ---- Phase A: softmax for this block's 64 rows (4 threads per row) ----
    const int rid = tid >> 2;            // 0..63
    const int part = tid & 3;            // k quarter
    const size_t base = (size_t)(row0 + rid) * SLK + part * 64;

    float4 v[16];
#pragma unroll
    for (int j = 0; j < 16; ++j) {
        float4 a = *(const float4*)&pbuf[base + j * 4];
        float4 c1 = *(const float4*)&pbuf[base + j * 4 + NPS];
        float4 c2 = *(const float4*)&pbuf[base + j * 4 + 2 * NPS];
        float4 c3 = *(const float4*)&pbuf[base + j * 4 + 3 * NPS];
        v[j].x = (a.x + c1.x) + (c2.x + c3.x);
        v[j].y = (a.y + c1.y) + (c2.y + c3.y);
        v[j].z = (a.z + c1.z) + (c2.z + c3.z);
        v[j].w = (a.w + c1.w) + (c2.w + c3.w);
    }
    float m = -3.0e38f;
#pragma unroll
    for (int j = 0; j < 16; ++j)
        m = fmaxf(m, fmaxf(fmaxf(v[j].x, v[j].y), fmaxf(v[j].z, v[j].w)));
    m = fmaxf(m, __shfl_xor(m, 1, 64));
    m = fmaxf(m, __shfl_xor(m, 2, 64));

    float s = 0.f;
#pragma unroll
    for (int j = 0; j < 16; ++j) {
        v[j].x = fexp2((v[j].x - m) * LOG2E);
        v[j].y = fexp2((v[j].y - m) * LOG2E);
        v[j].z = fexp2((v[j].z - m) * LOG2E);
        v[j].w = fexp2((v[j].w - m) * LOG2E);
        s += (v[j].x + v[j].y) + (v[j].z + v[j].w);
    }
    s += __shfl_xor(s, 1, 64);
    s += __shfl_xor(s, 2, 64);
    const float inv = 1.0f / s;

    const bool write_attn = (blockIdx.x == 0);
#pragma unroll
    for (int j = 0; j < 16; j += 2) {
        float4 p0, p1;
        p0.x = v[j].x * inv; p0.y = v[j].y * inv;
        p0.z = v[j].z * inv; p0.w = v[j].w * inv;
        p1.x = v[j + 1].x * inv; p1.y = v[j + 1].y * inv;
        p1.z = v[j + 1].z * inv; p1.w = v[j + 1].w * inv;
        f16x8 h;
        h[0] = (_Float16)p0.x; h[1] = (_Float16)p0.y;
        h[2] = (_Float16)p0.z; h[3] = (_Float16)p0.w;
        h[4] = (_Float16)p1.x; h[5] = (_Float16)p1.y;
        h[6] = (_Float16)p1.z; h[7] = (_Float16)p1.w;
        *(f16x8*)&Pl[rid * PSTR + part * 64 + j * 4] = h;
        if (write_attn) {
            *(float4*)&attnw[base + j * 4] = p0;
            *(float4*)&attnw[base + j * 4 + 4] = p1;
        }
    }

    // ---- Phase B: stage V panel [32 cols][256 k] ----
    {
        const _Float16* Bt = vsht + ((size_t)b * DD + col0) * SLK;
#pragma unroll
        for (int i = 0; i < 4; ++i) {
            const int u = tid + i * 256;     // 0..1023 f16x8 units
            const int c = u >> 5;            // col 0..31
            const int kseg = (u & 31) << 3;  // k 0..248
            *(f16x8*)&Vl[c * PSTR + kseg] = *(const f16x8*)&Bt[(size_t)c * SLK + kseg];
        }
    }

    __syncthreads();

    // ---- Phase C: P @ V, K=256 fully LDS-resident, no barriers ----
    const int lane = tid & 63;
    const int wid = tid >> 6;            // 16-row band
    const int fr = lane & 15;
    const int kj = (lane >> 4) << 3;
    const int band = wid << 4;

    f32x4 acc0 = {}, acc1 = {};
#pragma unroll
    for (int ks = 0; ks < 8; ++ks) {
        const int ko = ks * 32 + kj;
        f16x8 af = *(const f16x8*)&Pl[(band + fr) * PSTR + ko];
        f16x8 bf0 = *(const f16x8*)&Vl[fr * PSTR + ko];
        f16x8 bf1 = *(const f16x8*)&Vl[(16 + fr) * PSTR + ko];
        acc0 = __builtin_amdgcn_mfma_f32_16x16x32_f16(af, bf0, acc0, 0, 0, 0);
        acc1 = __builtin_amdgcn_mfma_f32_16x16x32_f16(af, bf1, acc1, 0, 0, 0);
    }

    float* C = out + (size_t)row0 * DD;
    const int colb = col0 + fr;
    const int rowb = band + ((lane >> 4) << 2);
#pragma unroll
    for (int r = 0; r < 4; ++r) {
        C[(size_t)(rowb + r) * DD + colb] = acc0[r];
        C[(size_t)(rowb + r) * DD + colb + 16] = acc1[r];
    }
}

extern "C" void kernel_launch(void* const* d_in, const int* in_sizes, int n_in,
                              void* d_out, int out_size, void* d_ws, size_t ws_size,
                              hipStream_t stream)
{
    (void)in_sizes; (void)n_in; (void)out_size; (void)ws_size;

    const float* query = (const float*)d_in[0];
    const float* key   = (const float*)d_in[1];
    const float* value = (const float*)d_in[2];
    const float* Wq = (const float*)d_in[3];
    const float* bq = (const float*)d_in[4];
    const float* Wk = (const float*)d_in[5];
    const float* bk = (const float*)d_in[6];
    const float* Wv = (const float*)d_in[7];
    const float* bv = (const float*)d_in[8];
    const float* Ws = (const float*)d_in[9];
    // d_in[10] (bs): softmax-invariant shift, unused.

    const size_t NE = (size_t)NB * SLQ * DD;   // 786432
    const size_t NW = (size_t)DD * DD;         // 589824

    char* w = (char*)d_ws;
    float* eq = (float*)w;               w += NE * 4;
    _Float16* ekc = (_Float16*)w;        w += NE * 2;
    _Float16* vsht = (_Float16*)w;       w += NE * 2;
    _Float16* wtq = (_Float16*)w;        w += NW * 2;
    _Float16* wtk = (_Float16*)w;        w += NW * 2;
    _Float16* wtv = (_Float16*)w;        w += NW * 2;
    float* pbuf = (float*)w;             // 4 * NPS f32 = 4 MB

    float* out = (float*)d_out;
    float* attended = out;               // [4,256,768]
    float* attnw = out + NE;             // [4,256,256]

    prep_wt_kernel<<<dim3(DD / 64, DD / 64, 3), 256, 0, stream>>>(
        Wq, Wk, Wv, wtq, wtk, wtv);
    qkv_f16_kernel<<<dim3(DD / 64, (NB * SLQ) / 64, 3), 256, 0, stream>>>(
        query, key, value, wtq, wtk, wtv, bq, bk, bv, eq, ekc, vsht);
    scores_partial_kernel<<<dim3(SLK / 64, SLQ / 8, NB * 4), 256, 0, stream>>>(
        eq, ekc, Ws, pbuf);
    attended_fused_kernel<<<dim3(DD / 32, (NB * SLQ) / 64, 1), 256, 0, stream>>>(
        pbuf, vsht, attnw, attended);
}

// Round 14
// 131.849 us; speedup vs baseline: 1.1324x; 1.1324x over previous
//
#include <hip/hip_runtime.h>

#define NB 4
#define SLQ 256
#define SLK 256
#define DD 768

// tanh(x) = 1 - 2/(1+e^{2x});  e^{2(q+k)} = exp2(q*2log2e)*exp2(k*2log2e).
// Softmax-invariant constants (sum Ws + bs) dropped from the logits.
#define TWO_LOG2E 2.8853900817779268f
#define LOG2E 1.4426950408889634f

typedef _Float16 f16x4 __attribute__((ext_vector_type(4)));
typedef _Float16 f16x8 __attribute__((ext_vector_type(8)));
typedef float f32x4 __attribute__((ext_vector_type(4)));

__device__ __forceinline__ float fexp2(float x) { return __builtin_amdgcn_exp2f(x); }
__device__ __forceinline__ float frcp(float x) { return __builtin_amdgcn_rcpf(x); }

#define LSTR 40            // LDS row stride (halves) for MFMA tiles
#define TSTR 72            // LDS row stride (halves) for f16 epilogue transpose
#define TFSTR 65           // LDS row stride (floats) for f32 epilogue restage
#define NPS  ((size_t)NB * SLQ * SLK)   // elements per scores-partial slice

// ---------------- Prep: W [in][out] fp32 -> Wt [out][in] fp16 ----------------
__global__ __launch_bounds__(256) void prep_wt_kernel(
    const float* __restrict__ Wq, const float* __restrict__ Wk,
    const float* __restrict__ Wv, _Float16* __restrict__ wtq,
    _Float16* __restrict__ wtk, _Float16* __restrict__ wtv)
{
    const int z = blockIdx.z;
    const float* W = (z == 0) ? Wq : (z == 1) ? Wk : Wv;
    _Float16* Wt = (z == 0) ? wtq : (z == 1) ? wtk : wtv;

    __shared__ float t[64][65];
    const int tid = threadIdx.x;
    const int kt0 = blockIdx.y * 64;
    const int nt0 = blockIdx.x * 64;

    const int col4 = (tid & 15) << 2;
#pragma unroll
    for (int i = 0; i < 4; ++i) {
        const int row = ((tid >> 4) << 2) + i;
        *(float4*)&t[row][col4] = *(const float4*)&W[(size_t)(kt0 + row) * DD + nt0 + col4];
    }
    __syncthreads();
    const int n = tid >> 2;
    const int k16 = (tid & 3) << 4;
    f16x8 h0, h1;
#pragma unroll
    for (int j = 0; j < 8; ++j) {
        h0[j] = (_Float16)t[k16 + j][n];
        h1[j] = (_Float16)t[k16 + 8 + j][n];
    }
    *(f16x8*)&Wt[(size_t)(nt0 + n) * DD + kt0 + k16] = h0;
    *(f16x8*)&Wt[(size_t)(nt0 + n) * DD + kt0 + k16 + 8] = h1;
}

// ---------------- QKV projection, fp16 MFMA, 512 threads (8 waves) ----------------
// 64x64 tile, BK=32; wave grid 2x4: each wave 32 rows x 16 cols = 2 MFMA/step.
// z=0 -> eq f32 = exp2(q*2log2e); z=1 -> ekc f16 chunked [b][d/8][k][8];
// z=2 -> vsht f16 = v^T [b][col][k] via LDS transpose.
__global__ __launch_bounds__(512) void qkv_f16_kernel(
    const float* __restrict__ query, const float* __restrict__ key_in,
    const float* __restrict__ value, const _Float16* __restrict__ wtq,
    const _Float16* __restrict__ wtk, const _Float16* __restrict__ wtv,
    const float* __restrict__ bq, const float* __restrict__ bk,
    const float* __restrict__ bv, float* __restrict__ eq,
    _Float16* __restrict__ ekc, _Float16* __restrict__ vsht)
{
    const int z = blockIdx.z;
    const float* A = (z == 0) ? query : (z == 1) ? key_in : value;
    const _Float16* Wt = (z == 0) ? wtq : (z == 1) ? wtk : wtv;
    const float* bias = (z == 0) ? bq : (z == 1) ? bk : bv;

    __shared__ _Float16 Sh[2][2][64 * LSTR];   // 20480 B; reused by epilogues

    const int tid = threadIdx.x;      // 0..511
    const int lane = tid & 63;
    const int wid = tid >> 6;         // 0..7
    const int wr = wid >> 2;          // 0..1 (32-row band)
    const int wc = wid & 3;           // 0..3 (16-col band)
    const int row0 = blockIdx.y * 64;
    const int col0 = blockIdx.x * 64;

    const int sr = tid >> 3;          // staged row / out-col 0..63
    const int sc = (tid & 7) << 2;    // k offset 0,4,...,28

    const float* Ap = A + (size_t)(row0 + sr) * DD + sc;
    const _Float16* Bp = Wt + (size_t)(col0 + sr) * DD + sc;

    float4 pa = *(const float4*)Ap;
    f16x4 pb = *(const f16x4*)Bp;

    f32x4 acc0 = {}, acc1 = {};
    const int kj = (lane >> 4) << 3;
    const int fr = lane & 15;

    {
        f16x4 ha;
        ha[0] = (_Float16)pa.x; ha[1] = (_Float16)pa.y;
        ha[2] = (_Float16)pa.z; ha[3] = (_Float16)pa.w;
        *(f16x4*)&Sh[0][0][sr * LSTR + sc] = ha;
        *(f16x4*)&Sh[0][1][sr * LSTR + sc] = pb;
    }
    __syncthreads();

    int p = 0;
    for (int s = 0; s < DD / 32; ++s) {
        if (s + 1 < DD / 32) {
            pa = *(const float4*)(Ap + (s + 1) * 32);
            pb = *(const f16x4*)(Bp + (s + 1) * 32);
        }
        f16x8 af0 = *(const f16x8*)&Sh[p][0][(wr * 32 + fr) * LSTR + kj];
        f16x8 af1 = *(const f16x8*)&Sh[p][0][(wr * 32 + 16 + fr) * LSTR + kj];
        f16x8 bf  = *(const f16x8*)&Sh[p][1][(wc * 16 + fr) * LSTR + kj];
        acc0 = __builtin_amdgcn_mfma_f32_16x16x32_f16(af0, bf, acc0, 0, 0, 0);
        acc1 = __builtin_amdgcn_mfma_f32_16x16x32_f16(af1, bf, acc1, 0, 0, 0);
        if (s + 1 < DD / 32) {
            f16x4 ha;
            ha[0] = (_Float16)pa.x; ha[1] = (_Float16)pa.y;
            ha[2] = (_Float16)pa.z; ha[3] = (_Float16)pa.w;
            *(f16x4*)&Sh[p ^ 1][0][sr * LSTR + sc] = ha;
            *(f16x4*)&Sh[p ^ 1][1][sr * LSTR + sc] = pb;
        }
        __syncthreads();
        p ^= 1;
    }

    // C/D layout: col = lane&15, row = (lane>>4)*4 + reg [m89 verified]
    const int clb = wc * 16 + fr;                 // local col (one 16-col band/wave)
    const int rlb = wr * 32 + ((lane >> 4) << 2); // local row base

    if (z < 2) {
        // stage exp2 values into LDS f32 tile, then coalesced stores
        float* Tf = (float*)Sh;   // [64][TFSTR] = 16.6 KB
        const float bvv = bias[col0 + clb];
#pragma unroll
        for (int mf = 0; mf < 2; ++mf) {
#pragma unroll
            for (int r = 0; r < 4; ++r) {
                const int rl = rlb + mf * 16 + r;
                const float a = (mf == 0) ? acc0[r] : acc1[r];
                const float arg = fminf((a + bvv) * TWO_LOG2E, 15.0f);
                Tf[rl * TFSTR + clb] = fexp2(arg);
            }
        }
        __syncthreads();
        if (z == 0) {
#pragma unroll
            for (int j = 0; j < 2; ++j) {
                const int u = tid + j * 512;       // 0..1023 float4 units
                const int row = u >> 4;
                const int c4 = (u & 15) << 2;
                float4 v = *(const float4*)&Tf[row * TFSTR + c4];
                *(float4*)&eq[(size_t)(row0 + row) * DD + col0 + c4] = v;
            }
        } else {
            const int b = row0 >> 8;
            const int krow0 = row0 & 255;
            const size_t base = (size_t)b * (SLK * DD) + (size_t)(col0 >> 3) * (SLK * 8);
            const int c2 = tid >> 6;               // chunk 0..7
            const int k = tid & 63;
            const float* src = &Tf[k * TFSTR + c2 * 8];
            f16x8 h;
#pragma unroll
            for (int i = 0; i < 8; ++i) h[i] = (_Float16)src[i];
            *(f16x8*)&ekc[base + (size_t)c2 * (SLK * 8) + (size_t)(krow0 + k) * 8] = h;
        }
    } else {
        // stage C^T in LDS (f16), then coalesced f16x8 stores to vsht[b][col][k]
        _Float16* T = (_Float16*)Sh;   // 64 cols x TSTR = 9.2 KB
        const float bvv = bias[col0 + clb];
#pragma unroll
        for (int mf = 0; mf < 2; ++mf) {
            const int rl = rlb + mf * 16;
            f16x4 h;
#pragma unroll
            for (int r = 0; r < 4; ++r)
                h[r] = (_Float16)(((mf == 0) ? acc0[r] : acc1[r]) + bvv);
            *(f16x4*)&T[clb * TSTR + rl] = h;
        }
        __syncthreads();
        const int b = row0 >> 8;
        const int krow0 = row0 & 255;
        const int c2 = tid >> 3;       // col 0..63
        const int g = tid & 7;         // k-octet
        f16x8 hv = *(const f16x8*)&T[c2 * TSTR + g * 8];
        *(f16x8*)&vsht[((size_t)b * DD + col0 + c2) * SLK + krow0 + g * 8] = hv;
    }
}

// ---------------- Scores partial (d-split S=4, 2 q-rows/thread, pairwise rcp) ----------------
__global__ __launch_bounds__(256) void scores_partial_kernel(
    const float* __restrict__ Eq, const _Float16* __restrict__ Ekc,
    const float* __restrict__ Ws, float* __restrict__ pbuf)
{
    const int bz = blockIdx.z;
    const int b = bz >> 2;
    const int s = bz & 3;
    const int k0 = blockIdx.x * 64;
    const int q0 = blockIdx.y * 8;
    const int lane = threadIdx.x & 63;
    const int wid = __builtin_amdgcn_readfirstlane((int)(threadIdx.x >> 6));
    const int q = q0 + (wid << 1);
    const int d0 = s * 192;

    const _Float16* kr = Ekc + (size_t)b * (SLK * DD) + ((d0 >> 3) * (SLK * 8)) +
                         (k0 + lane) * 8;
    const float* qp0 = Eq + (size_t)(b * SLQ + q) * DD + d0;
    const float* qp1 = qp0 + DD;
    const float* wp = Ws + d0;

    float acc0 = 0.f, acc1 = 0.f;

#pragma unroll 4
    for (int c = 0; c < 24; ++c) {
        const int dn = c * 8;
        f16x8 e = *(const f16x8*)(kr + (size_t)c * (SLK * 8));
        float4 ga0 = *(const float4*)(qp0 + dn);
        float4 ga1 = *(const float4*)(qp0 + dn + 4);
        float4 gb0 = *(const float4*)(qp1 + dn);
        float4 gb1 = *(const float4*)(qp1 + dn + 4);
        float4 w0 = *(const float4*)(wp + dn);
        float4 w1 = *(const float4*)(wp + dn + 4);

        float e0 = (float)e[0], e1 = (float)e[1], e2 = (float)e[2], e3 = (float)e[3];
        float e4 = (float)e[4], e5 = (float)e[5], e6 = (float)e[6], e7 = (float)e[7];

        {
            float A0 = fmaf(ga0.x, e0, 1.0f), A1 = fmaf(ga0.y, e1, 1.0f);
            float A2 = fmaf(ga0.z, e2, 1.0f), A3 = fmaf(ga0.w, e3, 1.0f);
            float A4 = fmaf(ga1.x, e4, 1.0f), A5 = fmaf(ga1.y, e5, 1.0f);
            float A6 = fmaf(ga1.z, e6, 1.0f), A7 = fmaf(ga1.w, e7, 1.0f);
            acc0 = fmaf(fmaf(w0.x, A1, w0.y * A0), frcp(A0 * A1), acc0);
            acc0 = fmaf(fmaf(w0.z, A3, w0.w * A2), frcp(A2 * A3), acc0);
            acc0 = fmaf(fmaf(w1.x, A5, w1.y * A4), frcp(A4 * A5), acc0);
            acc0 = fmaf(fmaf(w1.z, A7, w1.w * A6), frcp(A6 * A7), acc0);
        }
        {
            float A0 = fmaf(gb0.x, e0, 1.0f), A1 = fmaf(gb0.y, e1, 1.0f);
            float A2 = fmaf(gb0.z, e2, 1.0f), A3 = fmaf(gb0.w, e3, 1.0f);
            float A4 = fmaf(gb1.x, e4, 1.0f), A5 = fmaf(gb1.y, e5, 1.0f);
            float A6 = fmaf(gb1.z, e6, 1.0f), A7 = fmaf(gb1.w, e7, 1.0f);
            acc1 = fmaf(fmaf(w0.x, A1, w0.y * A0), frcp(A0 * A1), acc1);
            acc1 = fmaf(fmaf(w0.z, A3, w0.w * A2), frcp(A2 * A3), acc1);
            acc1 = fmaf(fmaf(w1.x, A5, w1.y * A4), frcp(A4 * A5), acc1);
            acc1 = fmaf(fmaf(w1.z, A7, w1.w * A6), frcp(A6 * A7), acc1);
        }
    }

    const size_t o = (size_t)s * NPS + (size_t)(b * SLQ + q) * SLK + k0 + lane;
    pbuf[o] = -2.0f * acc0;
    pbuf[o + SLK] = -2.0f * acc1;
}

// ---------------- Combine partials + softmax (one wave per row) ----------------
__global__ __launch_bounds__(256) void softmax_combine_kernel(
    const float* __restrict__ pbuf, float* __restrict__ attnw,
    _Float16* __restrict__ phalf)
{
    const int lane = threadIdx.x & 63;
    const int wv = threadIdx.x >> 6;
    const int row = blockIdx.x * 4 + wv;     // 0..1023
    const size_t base = (size_t)row * SLK + (lane << 2);

    float4 x0 = *(const float4*)&pbuf[base];
    float4 x1 = *(const float4*)&pbuf[base + NPS];
    float4 x2 = *(const float4*)&pbuf[base + 2 * NPS];
    float4 x3 = *(const float4*)&pbuf[base + 3 * NPS];
    float4 x;
    x.x = (x0.x + x1.x) + (x2.x + x3.x);
    x.y = (x0.y + x1.y) + (x2.y + x3.y);
    x.z = (x0.z + x1.z) + (x2.z + x3.z);
    x.w = (x0.w + x1.w) + (x2.w + x3.w);

    float m = fmaxf(fmaxf(x.x, x.y), fmaxf(x.z, x.w));
#pragma unroll
    for (int off = 32; off; off >>= 1) m = fmaxf(m, __shfl_xor(m, off, 64));

    float e0 = fexp2((x.x - m) * LOG2E);
    float e1 = fexp2((x.y - m) * LOG2E);
    float e2 = fexp2((x.z - m) * LOG2E);
    float e3 = fexp2((x.w - m) * LOG2E);
    float sm = (e0 + e1) + (e2 + e3);
#pragma unroll
    for (int off = 32; off; off >>= 1) sm += __shfl_xor(sm, off, 64);

    const float inv = 1.0f / sm;
    float4 o;
    o.x = e0 * inv; o.y = e1 * inv; o.z = e2 * inv; o.w = e3 * inv;
    *(float4*)&attnw[base] = o;

    f16x4 h;
    h[0] = (_Float16)o.x; h[1] = (_Float16)o.y;
    h[2] = (_Float16)o.z; h[3] = (_Float16)o.w;
    *(f16x4*)&phalf[base] = h;
}

// ---------------- Attended: out = P @ V, fp16 MFMA, 64x32 tiles (384 blocks) ----------------
__global__ __launch_bounds__(256) void attended_f16_kernel(
    const _Float16* __restrict__ phalf, const _Float16* __restrict__ vsht,
    float* __restrict__ out)
{
    const int row0 = blockIdx.y * 64;    // 0..960 (stays within batch)
    const int col0 = blockIdx.x * 32;    // 0..736
    const int b = row0 >> 8;
    const _Float16* Bt = vsht + (size_t)b * DD * SLK;
    float* C = out + (size_t)(row0)*DD;  // rows are global (b folded in)

    __shared__ _Float16 Ah[2][64 * LSTR];
    __shared__ _Float16 Bh[2][32 * LSTR];

    const int tid = threadIdx.x;
    const int lane = tid & 63;
    const int wid = tid >> 6;            // wave -> 16-row band

    const int sr = tid >> 2;             // A row 0..63
    const int sc = (tid & 3) << 3;       // k offset 0,8,16,24
    const int br = tid >> 2;             // B col 0..31 (tid<128)
    const int bc = (tid & 3) << 3;

    const _Float16* Ap = phalf + (size_t)(row0 + sr) * SLK + sc;
    const _Float16* Bp = Bt + (size_t)(col0 + br) * SLK + bc;

    f16x8 pa = *(const f16x8*)Ap;
    f16x8 pb;
    if (tid < 128) pb = *(const f16x8*)Bp;

    f32x4 acc0 = {}, acc1 = {};
    const int kj = (lane >> 4) << 3;
    const int fr = lane & 15;

    *(f16x8*)&Ah[0][sr * LSTR + sc] = pa;
    if (tid < 128) *(f16x8*)&Bh[0][br * LSTR + bc] = pb;
    __syncthreads();

    int p = 0;
    for (int s = 0; s < SLK / 32; ++s) {
        if (s + 1 < SLK / 32) {
            pa = *(const f16x8*)(Ap + (s + 1) * 32);
            if (tid < 128) pb = *(const f16x8*)(Bp + (s + 1) * 32);
        }
        f16x8 af = *(const f16x8*)&Ah[p][(wid * 16 + fr) * LSTR + kj];
        f16x8 bf0 = *(const f16x8*)&Bh[p][fr * LSTR + kj];
        f16x8 bf1 = *(const f16x8*)&Bh[p][(16 + fr) * LSTR + kj];
        acc0 = __builtin_amdgcn_mfma_f32_16x16x32_f16(af, bf0, acc0, 0, 0, 0);
        acc1 = __builtin_amdgcn_mfma_f32_16x16x32_f16(af, bf1, acc1, 0, 0, 0);
        if (s + 1 < SLK / 32) {
            *(f16x8*)&Ah[p ^ 1][sr * LSTR + sc] = pa;
            if (tid < 128) *(f16x8*)&Bh[p ^ 1][br * LSTR + bc] = pb;
        }
        __syncthreads();
        p ^= 1;
    }

    const int colb = col0 + fr;
    const int rowb = wid * 16 + ((lane >> 4) << 2);
#pragma unroll
    for (int r = 0; r < 4; ++r) {
        C[(size_t)(rowb + r) * DD + colb] = acc0[r];
        C[(size_t)(rowb + r) * DD + colb + 16] = acc1[r];
    }
}

extern "C" void kernel_launch(void* const* d_in, const int* in_sizes, int n_in,
                              void* d_out, int out_size, void* d_ws, size_t ws_size,
                              hipStream_t stream)
{
    (void)in_sizes; (void)n_in; (void)out_size; (void)ws_size;

    const float* query = (const float*)d_in[0];
    const float* key   = (const float*)d_in[1];
    const float* value = (const float*)d_in[2];
    const float* Wq = (const float*)d_in[3];
    const float* bq = (const float*)d_in[4];
    const float* Wk = (const float*)d_in[5];
    const float* bk = (const float*)d_in[6];
    const float* Wv = (const float*)d_in[7];
    const float* bv = (const float*)d_in[8];
    const float* Ws = (const float*)d_in[9];
    // d_in[10] (bs): softmax-invariant shift, unused.

    const size_t NE = (size_t)NB * SLQ * DD;   // 786432
    const size_t NW = (size_t)DD * DD;         // 589824

    char* w = (char*)d_ws;
    float* eq = (float*)w;               w += NE * 4;
    _Float16* ekc = (_Float16*)w;        w += NE * 2;
    _Float16* vsht = (_Float16*)w;       w += NE * 2;
    _Float16* phalf = (_Float16*)w;      w += NPS * 2;
    _Float16* wtq = (_Float16*)w;        w += NW * 2;
    _Float16* wtk = (_Float16*)w;        w += NW * 2;
    _Float16* wtv = (_Float16*)w;        w += NW * 2;
    float* pbuf = (float*)w;             // 4 * NPS f32 = 4 MB

    float* out = (float*)d_out;
    float* attended = out;               // [4,256,768]
    float* attnw = out + NE;             // [4,256,256]

    prep_wt_kernel<<<dim3(DD / 64, DD / 64, 3), 256, 0, stream>>>(
        Wq, Wk, Wv, wtq, wtk, wtv);
    qkv_f16_kernel<<<dim3(DD / 64, (NB * SLQ) / 64, 3), 512, 0, stream>>>(
        query, key, value, wtq, wtk, wtv, bq, bk, bv, eq, ekc, vsht);
    scores_partial_kernel<<<dim3(SLK / 64, SLQ / 8, NB * 4), 256, 0, stream>>>(
        eq, ekc, Ws, pbuf);
    softmax_combine_kernel<<<dim3((NB * SLQ) / 4), 256, 0, stream>>>(
        pbuf, attnw, phalf);
    attended_f16_kernel<<<dim3(DD / 32, (NB * SLQ) / 64, 1), 256, 0, stream>>>(
        phalf, vsht, attended);
}